// Round 3
// baseline (731.188 us; speedup 1.0000x reference)
//
#include <hip/hip_runtime.h>
#include <hip/hip_bf16.h>

typedef __hip_bfloat16 bf16;

#define N_NODES 100000
#define N_EDGES 1600000
// IN_C=128, HEADS=8, OUT_C=8, ACTUAL_OUT=64, EDGE_DIM=4

__device__ __forceinline__ float rlane(float v, int l) {
    return __int_as_float(__builtin_amdgcn_readlane(__float_as_int(v), l));
}

// ---------------- K_AE: fold W_edge (4x64) with att_edge (8x8) -> AE[4][8] ----
__global__ void k_ae(const float* __restrict__ W_edge,
                     const float* __restrict__ att_edge, float* __restrict__ AE) {
    int t = threadIdx.x;
    if (t < 32) {
        int d = t >> 3, hd = t & 7;
        float s = 0.f;
        #pragma unroll
        for (int c = 0; c < 8; ++c)
            s += W_edge[d * 64 + hd * 8 + c] * att_edge[hd * 8 + c];
        AE[t] = s;  // AE[d*8+hd]
    }
}

// ---------------- K1: h = x@W (->bf16), ident = x@res_W + res_b (-> d_out),
//                  a_src/a_dst per node.
// Block = 256 thr (4 waves). Weights (128x128: W | res_W) staged in LDS (64KB).
// Each wave handles 8 nodes; x rows live in lanes, broadcast via v_readlane.
__global__ __launch_bounds__(256) void k1_node(
    const float* __restrict__ x, const float* __restrict__ W,
    const float* __restrict__ resW, const float* __restrict__ att_src,
    const float* __restrict__ att_dst, const float* __restrict__ res_b,
    bf16* __restrict__ h, float* __restrict__ ident,
    float* __restrict__ a_src, float* __restrict__ a_dst)
{
    __shared__ float wl[128 * 128];  // wl[k*128 + j]; j<64: W[k][j], j>=64: resW[k][j-64]
    const int tid = threadIdx.x;
    for (int i = tid; i < 8192; i += 256) {
        int k = i >> 6, j = i & 63;
        wl[k * 128 + j] = W[i];          // coalesced read, conflict-free write
        wl[k * 128 + 64 + j] = resW[i];
    }
    __syncthreads();

    const int lane = tid & 63;
    const int wid = tid >> 6;
    const float asv = att_src[lane];  // att_src[hd][c], hd=lane>>3, c=lane&7
    const float adv = att_dst[lane];
    const float rbv = res_b[lane];

    for (int g = 0; g < 4; ++g) {
        const int nbase = blockIdx.x * 128 + g * 32 + wid * 8;
        float xlo[8], xhi[8], ah[8], ai[8];
        #pragma unroll
        for (int r = 0; r < 8; ++r) {
            const int n = nbase + r;
            if (n < N_NODES) {   // wave-uniform branch
                xlo[r] = x[(size_t)n * 128 + lane];
                xhi[r] = x[(size_t)n * 128 + 64 + lane];
            } else { xlo[r] = 0.f; xhi[r] = 0.f; }
            ah[r] = 0.f; ai[r] = 0.f;
        }
        #pragma unroll 4
        for (int k = 0; k < 64; ++k) {
            const float w0 = wl[k * 128 + lane];        // 2-way LDS alias: free
            const float w1 = wl[k * 128 + 64 + lane];
            #pragma unroll
            for (int r = 0; r < 8; ++r) {
                const float xv = rlane(xlo[r], k);
                ah[r] = fmaf(w0, xv, ah[r]);
                ai[r] = fmaf(w1, xv, ai[r]);
            }
        }
        #pragma unroll 4
        for (int k = 64; k < 128; ++k) {
            const float w0 = wl[k * 128 + lane];
            const float w1 = wl[k * 128 + 64 + lane];
            #pragma unroll
            for (int r = 0; r < 8; ++r) {
                const float xv = rlane(xhi[r], k - 64);
                ah[r] = fmaf(w0, xv, ah[r]);
                ai[r] = fmaf(w1, xv, ai[r]);
            }
        }
        #pragma unroll
        for (int r = 0; r < 8; ++r) {
            const int n = nbase + r;
            float ps = ah[r] * asv;
            float pd = ah[r] * adv;
            ps += __shfl_xor(ps, 1); ps += __shfl_xor(ps, 2); ps += __shfl_xor(ps, 4);
            pd += __shfl_xor(pd, 1); pd += __shfl_xor(pd, 2); pd += __shfl_xor(pd, 4);
            if (n < N_NODES) {
                h[(size_t)n * 64 + lane] = __float2bfloat16(ah[r]);
                ident[(size_t)n * 64 + lane] = ai[r] + rbv;
                if ((lane & 7) == 0) {
                    a_src[n * 8 + (lane >> 3)] = ps;
                    a_dst[n * 8 + (lane >> 3)] = pd;
                }
            }
        }
    }
}

// ---------------- K2: edge pass. One wave per edge; lane = output channel. ----
// num = exp(leaky(a_src[s]+a_dst[d]+ea@AE));  o_raw[d] += num*h[s]; denom[d]+=num
__global__ __launch_bounds__(256) void k2_edge(
    const int* __restrict__ ei, const float* __restrict__ ea,
    const bf16* __restrict__ h, const float* __restrict__ a_src,
    const float* __restrict__ a_dst, const float* __restrict__ AE,
    float* __restrict__ denom, float* __restrict__ out_raw)
{
    const int lane = threadIdx.x & 63;
    const int hd = lane >> 3;
    const float ae0 = AE[hd], ae1 = AE[8 + hd], ae2 = AE[16 + hd], ae3 = AE[24 + hd];
    const int estride = gridDim.x * 4;
    for (int e = blockIdx.x * 4 + (threadIdx.x >> 6); e < N_EDGES; e += estride) {
        const int src = ei[e];
        const int dst = ei[N_EDGES + e];
        const float hv = __bfloat162float(h[(size_t)src * 64 + lane]);  // 128B coalesced gather
        const float4 eav = *reinterpret_cast<const float4*>(ea + (size_t)e * 4);
        float logit = a_src[src * 8 + hd] + a_dst[dst * 8 + hd]
                    + eav.x * ae0 + eav.y * ae1 + eav.z * ae2 + eav.w * ae3;
        logit = logit > 0.f ? logit : 0.2f * logit;   // leaky_relu 0.2
        const float num = __expf(logit);              // no max-shift: alpha invariant
        atomicAdd(&out_raw[(size_t)dst * 64 + lane], num * hv);
        if ((lane & 7) == 0) atomicAdd(&denom[dst * 8 + hd], num);
    }
}

// ---------------- K3: o_raw <- o_raw/denom + bias (in place), BN partials ----
__global__ __launch_bounds__(256) void k3_norm_stats(
    float* __restrict__ out_raw, const float* __restrict__ denom,
    const float* __restrict__ bias,
    float* __restrict__ bn_acc /* [128]: sum(64), sumsq(64) */)
{
    const int tid = threadIdx.x;
    const int c = tid & 63;
    const float b = bias[c];
    float s1 = 0.f, s2 = 0.f;
    const int stride = gridDim.x * 4;
    for (int n = blockIdx.x * 4 + (tid >> 6); n < N_NODES; n += stride) {
        const float v = out_raw[(size_t)n * 64 + c] / (denom[n * 8 + (c >> 3)] + 1e-16f) + b;
        out_raw[(size_t)n * 64 + c] = v;
        s1 += v; s2 += v * v;
    }
    __shared__ float r1[256], r2[256];
    r1[tid] = s1; r2[tid] = s2;
    __syncthreads();
    if (tid < 64) {
        s1 = r1[tid] + r1[tid + 64] + r1[tid + 128] + r1[tid + 192];
        s2 = r2[tid] + r2[tid + 64] + r2[tid + 128] + r2[tid + 192];
        atomicAdd(&bn_acc[c], s1);
        atomicAdd(&bn_acc[64 + c], s2);
    }
}

// ---------------- K3b: per-channel scale/shift from accumulated stats ---------
__global__ void k3b_stats(const float* __restrict__ bn_acc,
                          const float* __restrict__ bn_w,
                          const float* __restrict__ bn_b, float* __restrict__ scsh) {
    int c = threadIdx.x;
    if (c < 64) {
        const float inv_n = 1.0f / (float)N_NODES;
        const float mean = bn_acc[c] * inv_n;
        const float var = bn_acc[64 + c] * inv_n - mean * mean;  // biased var
        const float sc = bn_w[c] * rsqrtf(var + 1e-5f);
        scsh[c] = sc;
        scsh[64 + c] = bn_b[c] - mean * sc;
    }
}

// ---------------- K4: out = ELU(v*sc+sh) + ident, float4-vectorized ----------
// v lives in o_raw, ident lives in d_out (written by K1); final -> d_out.
__global__ __launch_bounds__(256) void k4_final(
    float* __restrict__ out, const float* __restrict__ vbuf,
    const float* __restrict__ scsh)
{
    __shared__ float4 sc4[16], sh4[16];
    if (threadIdx.x < 16) {
        sc4[threadIdx.x] = reinterpret_cast<const float4*>(scsh)[threadIdx.x];
        sh4[threadIdx.x] = reinterpret_cast<const float4*>(scsh + 64)[threadIdx.x];
    }
    __syncthreads();
    float4* o4 = reinterpret_cast<float4*>(out);
    const float4* v4 = reinterpret_cast<const float4*>(vbuf);
    const int total = N_NODES * 16;
    for (int i = blockIdx.x * 256 + threadIdx.x; i < total; i += gridDim.x * 256) {
        float4 v = v4[i];
        float4 id = o4[i];
        const float4 s = sc4[i & 15];
        const float4 t = sh4[i & 15];
        v.x = v.x * s.x + t.x; v.x = (v.x > 0.f ? v.x : __expf(v.x) - 1.f) + id.x;
        v.y = v.y * s.y + t.y; v.y = (v.y > 0.f ? v.y : __expf(v.y) - 1.f) + id.y;
        v.z = v.z * s.z + t.z; v.z = (v.z > 0.f ? v.z : __expf(v.z) - 1.f) + id.z;
        v.w = v.w * s.w + t.w; v.w = (v.w > 0.f ? v.w : __expf(v.w) - 1.f) + id.w;
        o4[i] = v;
    }
}

extern "C" void kernel_launch(void* const* d_in, const int* in_sizes, int n_in,
                              void* d_out, int out_size, void* d_ws, size_t ws_size,
                              hipStream_t stream) {
    const float* x        = (const float*)d_in[0];
    const int*   ei       = (const int*)  d_in[1];   // harness converts integer -> int32
    const float* ea       = (const float*)d_in[2];
    const float* W        = (const float*)d_in[3];
    const float* att_src  = (const float*)d_in[4];
    const float* att_dst  = (const float*)d_in[5];
    const float* W_edge   = (const float*)d_in[6];
    const float* att_edge = (const float*)d_in[7];
    const float* bias     = (const float*)d_in[8];
    const float* bn_w     = (const float*)d_in[9];
    const float* bn_b     = (const float*)d_in[10];
    const float* res_W    = (const float*)d_in[11];
    const float* res_b    = (const float*)d_in[12];

    char* ws = (char*)d_ws;
    size_t off = 0;
    bf16*  h      = (bf16*) (ws + off); off += (size_t)N_NODES * 64 * 2;
    float* a_src  = (float*)(ws + off); off += (size_t)N_NODES * 8 * 4;
    float* a_dst  = (float*)(ws + off); off += (size_t)N_NODES * 8 * 4;
    char*  zstart = ws + off;
    float* denom  = (float*)(ws + off); off += (size_t)N_NODES * 8 * 4;
    float* o_raw  = (float*)(ws + off); off += (size_t)N_NODES * 64 * 4;
    float* bn_acc = (float*)(ws + off); off += 128 * 4;
    size_t zbytes = (size_t)((ws + off) - zstart);
    float* scsh   = (float*)(ws + off); off += 128 * 4;
    float* AE     = (float*)(ws + off); off += 32 * 4;

    float* ident = (float*)d_out;  // K1 writes residual GEMV here; K4 fuses in place

    hipMemsetAsync(zstart, 0, zbytes, stream);
    k_ae<<<1, 64, 0, stream>>>(W_edge, att_edge, AE);
    k1_node<<<(N_NODES + 127) / 128, 256, 0, stream>>>(
        x, W, res_W, att_src, att_dst, res_b, h, ident, a_src, a_dst);
    k2_edge<<<16384, 256, 0, stream>>>(ei, ea, h, a_src, a_dst, AE, denom, o_raw);
    k3_norm_stats<<<2048, 256, 0, stream>>>(o_raw, denom, bias, bn_acc);
    k3b_stats<<<1, 64, 0, stream>>>(bn_acc, bn_w, bn_b, scsh);
    k4_final<<<2048, 256, 0, stream>>>((float*)d_out, o_raw, scsh);
}

// Round 5
// 620.208 us; speedup vs baseline: 1.1789x; 1.1789x over previous
//
#include <hip/hip_runtime.h>
#include <hip/hip_bf16.h>

#define N_NODES 100000
#define N_EDGES 1600000
// IN_C=128, HEADS=8, OUT_C=8, ACTUAL_OUT=64, EDGE_DIM=4

typedef unsigned short ushort_t;

__device__ __forceinline__ float rlane(float v, int l) {
    return __int_as_float(__builtin_amdgcn_readlane(__float_as_int(v), l));
}
// f32 -> bf16 bits (round-nearest-even), and back
__device__ __forceinline__ ushort_t f2bf(float f) {
    unsigned u = __float_as_uint(f);
    u += 0x7FFFu + ((u >> 16) & 1u);
    return (ushort_t)(u >> 16);
}
__device__ __forceinline__ float bf2f(ushort_t b) {
    return __uint_as_float((unsigned)b << 16);
}
// packed bf16x2 atomic add, device scope (sc1). gfx950 HW instruction.
__device__ __forceinline__ void atomic_pk_add_bf16(ushort_t* addr, unsigned packed) {
    asm volatile("global_atomic_pk_add_bf16 %0, %1, off sc1"
                 :: "v"(addr), "v"(packed) : "memory");
}

// ---------------- K_AE: fold W_edge (4x64) with att_edge (8x8) -> AE[4][8] ----
__global__ void k_ae(const float* __restrict__ W_edge,
                     const float* __restrict__ att_edge, float* __restrict__ AE) {
    int t = threadIdx.x;
    if (t < 32) {
        int d = t >> 3, hd = t & 7;
        float s = 0.f;
        #pragma unroll
        for (int c = 0; c < 8; ++c)
            s += W_edge[d * 64 + hd * 8 + c] * att_edge[hd * 8 + c];
        AE[t] = s;  // AE[d*8+hd]
    }
}

// ---------------- K1: h = x@W (->bf16), ident = x@res_W + res_b (-> d_out),
//                  a_src/a_dst per node.
__global__ __launch_bounds__(256) void k1_node(
    const float* __restrict__ x, const float* __restrict__ W,
    const float* __restrict__ resW, const float* __restrict__ att_src,
    const float* __restrict__ att_dst, const float* __restrict__ res_b,
    ushort_t* __restrict__ h, float* __restrict__ ident,
    float* __restrict__ a_src, float* __restrict__ a_dst)
{
    __shared__ float wl[128 * 128];  // wl[k*128 + j]; j<64: W[k][j], j>=64: resW[k][j-64]
    const int tid = threadIdx.x;
    for (int i = tid; i < 8192; i += 256) {
        int k = i >> 6, j = i & 63;
        wl[k * 128 + j] = W[i];
        wl[k * 128 + 64 + j] = resW[i];
    }
    __syncthreads();

    const int lane = tid & 63;
    const int wid = tid >> 6;
    const float asv = att_src[lane];
    const float adv = att_dst[lane];
    const float rbv = res_b[lane];

    for (int g = 0; g < 4; ++g) {
        const int nbase = blockIdx.x * 128 + g * 32 + wid * 8;
        float xlo[8], xhi[8], ah[8], ai[8];
        #pragma unroll
        for (int r = 0; r < 8; ++r) {
            const int n = nbase + r;
            if (n < N_NODES) {
                xlo[r] = x[(size_t)n * 128 + lane];
                xhi[r] = x[(size_t)n * 128 + 64 + lane];
            } else { xlo[r] = 0.f; xhi[r] = 0.f; }
            ah[r] = 0.f; ai[r] = 0.f;
        }
        #pragma unroll 4
        for (int k = 0; k < 64; ++k) {
            const float w0 = wl[k * 128 + lane];
            const float w1 = wl[k * 128 + 64 + lane];
            #pragma unroll
            for (int r = 0; r < 8; ++r) {
                const float xv = rlane(xlo[r], k);
                ah[r] = fmaf(w0, xv, ah[r]);
                ai[r] = fmaf(w1, xv, ai[r]);
            }
        }
        #pragma unroll 4
        for (int k = 64; k < 128; ++k) {
            const float w0 = wl[k * 128 + lane];
            const float w1 = wl[k * 128 + 64 + lane];
            #pragma unroll
            for (int r = 0; r < 8; ++r) {
                const float xv = rlane(xhi[r], k - 64);
                ah[r] = fmaf(w0, xv, ah[r]);
                ai[r] = fmaf(w1, xv, ai[r]);
            }
        }
        #pragma unroll
        for (int r = 0; r < 8; ++r) {
            const int n = nbase + r;
            float ps = ah[r] * asv;
            float pd = ah[r] * adv;
            ps += __shfl_xor(ps, 1); ps += __shfl_xor(ps, 2); ps += __shfl_xor(ps, 4);
            pd += __shfl_xor(pd, 1); pd += __shfl_xor(pd, 2); pd += __shfl_xor(pd, 4);
            if (n < N_NODES) {
                h[(size_t)n * 64 + lane] = f2bf(ah[r]);
                ident[(size_t)n * 64 + lane] = ai[r] + rbv;
                if ((lane & 7) == 0) {
                    a_src[n * 8 + (lane >> 3)] = ps;
                    a_dst[n * 8 + (lane >> 3)] = pd;
                }
            }
        }
    }
}

// ---------------- K2: edge pass. One wave per edge; lane = output channel. ----
// num = exp(leaky(a_src[s]+a_dst[d]+ea@AE));
// o_raw[d] += num*h[s] via packed bf16x2 atomics (even lanes); denom[d]+=num (f32)
__global__ __launch_bounds__(256) void k2_edge(
    const int* __restrict__ ei, const float* __restrict__ ea,
    const ushort_t* __restrict__ h, const float* __restrict__ a_src,
    const float* __restrict__ a_dst, const float* __restrict__ AE,
    float* __restrict__ denom, ushort_t* __restrict__ out_raw)
{
    const int lane = threadIdx.x & 63;
    const int hd = lane >> 3;
    const float ae0 = AE[hd], ae1 = AE[8 + hd], ae2 = AE[16 + hd], ae3 = AE[24 + hd];
    const int estride = gridDim.x * 4;
    for (int e = blockIdx.x * 4 + (threadIdx.x >> 6); e < N_EDGES; e += estride) {
        const int src = ei[e];
        const int dst = ei[N_EDGES + e];
        const float hv = bf2f(h[(size_t)src * 64 + lane]);  // 128B coalesced gather
        const float4 eav = *reinterpret_cast<const float4*>(ea + (size_t)e * 4);
        float logit = a_src[src * 8 + hd] + a_dst[dst * 8 + hd]
                    + eav.x * ae0 + eav.y * ae1 + eav.z * ae2 + eav.w * ae3;
        logit = logit > 0.f ? logit : 0.2f * logit;   // leaky_relu 0.2
        const float num = __expf(logit);              // no max-shift: alpha invariant
        const float v = num * hv;
        const float vn = __shfl_xor(v, 1);            // neighbor channel's term
        if ((lane & 1) == 0) {
            const unsigned packed = (unsigned)f2bf(v) | ((unsigned)f2bf(vn) << 16);
            atomic_pk_add_bf16(out_raw + (size_t)dst * 64 + lane, packed);
        }
        if ((lane & 7) == 0) atomicAdd(&denom[dst * 8 + hd], num);
    }
}

// ---------------- K3: BN partial stats from v = o_raw/denom + bias (no store) -
__global__ __launch_bounds__(256) void k3_stats(
    const ushort_t* __restrict__ out_raw, const float* __restrict__ denom,
    const float* __restrict__ bias,
    float* __restrict__ bn_acc /* [128]: sum(64), sumsq(64) */)
{
    const int tid = threadIdx.x;
    const int c = tid & 63;
    const float b = bias[c];
    float s1 = 0.f, s2 = 0.f;
    const int stride = gridDim.x * 4;
    for (int n = blockIdx.x * 4 + (tid >> 6); n < N_NODES; n += stride) {
        const float v = bf2f(out_raw[(size_t)n * 64 + c])
                        / (denom[n * 8 + (c >> 3)] + 1e-16f) + b;
        s1 += v; s2 += v * v;
    }
    __shared__ float r1[256], r2[256];
    r1[tid] = s1; r2[tid] = s2;
    __syncthreads();
    if (tid < 64) {
        s1 = r1[tid] + r1[tid + 64] + r1[tid + 128] + r1[tid + 192];
        s2 = r2[tid] + r2[tid + 64] + r2[tid + 128] + r2[tid + 192];
        atomicAdd(&bn_acc[c], s1);
        atomicAdd(&bn_acc[64 + c], s2);
    }
}

// ---------------- K3b: per-channel scale/shift from accumulated stats ---------
__global__ void k3b_stats(const float* __restrict__ bn_acc,
                          const float* __restrict__ bn_w,
                          const float* __restrict__ bn_b, float* __restrict__ scsh) {
    int c = threadIdx.x;
    if (c < 64) {
        const float inv_n = 1.0f / (float)N_NODES;
        const float mean = bn_acc[c] * inv_n;
        const float var = bn_acc[64 + c] * inv_n - mean * mean;  // biased var
        const float sc = bn_w[c] * rsqrtf(var + 1e-5f);
        scsh[c] = sc;
        scsh[64 + c] = bn_b[c] - mean * sc;
    }
}

// ---------------- K4: recompute v, BN affine + ELU + residual (ident in d_out) -
__global__ __launch_bounds__(256) void k4_final(
    float* __restrict__ out, const ushort_t* __restrict__ out_raw,
    const float* __restrict__ denom, const float* __restrict__ bias,
    const float* __restrict__ scsh)
{
    const int tid = threadIdx.x;
    const int c = tid & 63;
    const float b = bias[c];
    const float sc = scsh[c];
    const float sh = scsh[64 + c];
    const int stride = gridDim.x * 4;
    for (int n = blockIdx.x * 4 + (tid >> 6); n < N_NODES; n += stride) {
        float v = bf2f(out_raw[(size_t)n * 64 + c])
                  / (denom[n * 8 + (c >> 3)] + 1e-16f) + b;
        v = v * sc + sh;
        v = v > 0.f ? v : __expf(v) - 1.f;            // ELU
        out[(size_t)n * 64 + c] = v + out[(size_t)n * 64 + c];  // + ident
    }
}

extern "C" void kernel_launch(void* const* d_in, const int* in_sizes, int n_in,
                              void* d_out, int out_size, void* d_ws, size_t ws_size,
                              hipStream_t stream) {
    const float* x        = (const float*)d_in[0];
    const int*   ei       = (const int*)  d_in[1];
    const float* ea       = (const float*)d_in[2];
    const float* W        = (const float*)d_in[3];
    const float* att_src  = (const float*)d_in[4];
    const float* att_dst  = (const float*)d_in[5];
    const float* W_edge   = (const float*)d_in[6];
    const float* att_edge = (const float*)d_in[7];
    const float* bias     = (const float*)d_in[8];
    const float* bn_w     = (const float*)d_in[9];
    const float* bn_b     = (const float*)d_in[10];
    const float* res_W    = (const float*)d_in[11];
    const float* res_b    = (const float*)d_in[12];

    char* ws = (char*)d_ws;
    size_t off = 0;
    ushort_t* h   = (ushort_t*)(ws + off); off += (size_t)N_NODES * 64 * 2;
    float* a_src  = (float*)(ws + off); off += (size_t)N_NODES * 8 * 4;
    float* a_dst  = (float*)(ws + off); off += (size_t)N_NODES * 8 * 4;
    char*  zstart = ws + off;
    float* denom  = (float*)(ws + off); off += (size_t)N_NODES * 8 * 4;
    ushort_t* o_raw = (ushort_t*)(ws + off); off += (size_t)N_NODES * 64 * 2;
    float* bn_acc = (float*)(ws + off); off += 128 * 4;
    size_t zbytes = (size_t)((ws + off) - zstart);
    float* scsh   = (float*)(ws + off); off += 128 * 4;
    float* AE     = (float*)(ws + off); off += 32 * 4;

    float* ident = (float*)d_out;  // K1 writes residual GEMV here; K4 fuses in place

    (void)hipMemsetAsync(zstart, 0, zbytes, stream);
    k_ae<<<1, 64, 0, stream>>>(W_edge, att_edge, AE);
    k1_node<<<(N_NODES + 127) / 128, 256, 0, stream>>>(
        x, W, res_W, att_src, att_dst, res_b, h, ident, a_src, a_dst);
    k2_edge<<<16384, 256, 0, stream>>>(ei, ea, h, a_src, a_dst, AE, denom, o_raw);
    k3_stats<<<2048, 256, 0, stream>>>(o_raw, denom, bias, bn_acc);
    k3b_stats<<<1, 64, 0, stream>>>(bn_acc, bn_w, bn_b, scsh);
    k4_final<<<2048, 256, 0, stream>>>((float*)d_out, o_raw, denom, bias, scsh);
}

// Round 10
// 553.346 us; speedup vs baseline: 1.3214x; 1.1208x over previous
//
#include <hip/hip_runtime.h>
#include <hip/hip_bf16.h>

#define N_NODES 100000
#define N_EDGES 1600000
// IN_C=128, HEADS=8, OUT_C=8, ACTUAL_OUT=64, EDGE_DIM=4

typedef unsigned short ushort_t;

__device__ __forceinline__ float rlane(float v, int l) {
    return __int_as_float(__builtin_amdgcn_readlane(__float_as_int(v), l));
}
// f32 -> bf16 bits (round-nearest-even), and back
__device__ __forceinline__ ushort_t f2bf(float f) {
    unsigned u = __float_as_uint(f);
    u += 0x7FFFu + ((u >> 16) & 1u);
    return (ushort_t)(u >> 16);
}
__device__ __forceinline__ float bf2f(ushort_t b) {
    return __uint_as_float((unsigned)b << 16);
}
// packed bf16x2 atomic add, device scope (sc1). gfx950 HW instruction.
// NOTE: asm vmem op is invisible to the compiler's vmcnt bookkeeping -> caller
// MUST drain with s_waitcnt vmcnt(0) before wave exit (see end of k2_edge).
__device__ __forceinline__ void atomic_pk_add_bf16(ushort_t* addr, unsigned packed) {
    asm volatile("global_atomic_pk_add_bf16 %0, %1, off sc1"
                 :: "v"(addr), "v"(packed) : "memory");
}

// ---------------- K1: h = x@W (->bf16), ident = x@res_W + res_b (-> d_out),
//                  a_src/a_dst per node.
__global__ __launch_bounds__(256) void k1_node(
    const float* __restrict__ x, const float* __restrict__ W,
    const float* __restrict__ resW, const float* __restrict__ att_src,
    const float* __restrict__ att_dst, const float* __restrict__ res_b,
    ushort_t* __restrict__ h, float* __restrict__ ident,
    float* __restrict__ a_src, float* __restrict__ a_dst)
{
    __shared__ float wl[128 * 128];  // wl[k*128 + j]; j<64: W[k][j], j>=64: resW[k][j-64]
    const int tid = threadIdx.x;
    for (int i = tid; i < 8192; i += 256) {
        int k = i >> 6, j = i & 63;
        wl[k * 128 + j] = W[i];
        wl[k * 128 + 64 + j] = resW[i];
    }
    __syncthreads();

    const int lane = tid & 63;
    const int wid = tid >> 6;
    const float asv = att_src[lane];
    const float adv = att_dst[lane];
    const float rbv = res_b[lane];

    for (int g = 0; g < 4; ++g) {
        const int nbase = blockIdx.x * 128 + g * 32 + wid * 8;
        float xlo[8], xhi[8], ah[8], ai[8];
        #pragma unroll
        for (int r = 0; r < 8; ++r) {
            const int n = nbase + r;
            if (n < N_NODES) {
                xlo[r] = x[(size_t)n * 128 + lane];
                xhi[r] = x[(size_t)n * 128 + 64 + lane];
            } else { xlo[r] = 0.f; xhi[r] = 0.f; }
            ah[r] = 0.f; ai[r] = 0.f;
        }
        #pragma unroll 4
        for (int k = 0; k < 64; ++k) {
            const float w0 = wl[k * 128 + lane];
            const float w1 = wl[k * 128 + 64 + lane];
            #pragma unroll
            for (int r = 0; r < 8; ++r) {
                const float xv = rlane(xlo[r], k);
                ah[r] = fmaf(w0, xv, ah[r]);
                ai[r] = fmaf(w1, xv, ai[r]);
            }
        }
        #pragma unroll 4
        for (int k = 64; k < 128; ++k) {
            const float w0 = wl[k * 128 + lane];
            const float w1 = wl[k * 128 + 64 + lane];
            #pragma unroll
            for (int r = 0; r < 8; ++r) {
                const float xv = rlane(xhi[r], k - 64);
                ah[r] = fmaf(w0, xv, ah[r]);
                ai[r] = fmaf(w1, xv, ai[r]);
            }
        }
        #pragma unroll
        for (int r = 0; r < 8; ++r) {
            const int n = nbase + r;
            float ps = ah[r] * asv;
            float pd = ah[r] * adv;
            ps += __shfl_xor(ps, 1); ps += __shfl_xor(ps, 2); ps += __shfl_xor(ps, 4);
            pd += __shfl_xor(pd, 1); pd += __shfl_xor(pd, 2); pd += __shfl_xor(pd, 4);
            if (n < N_NODES) {
                h[(size_t)n * 64 + lane] = f2bf(ah[r]);
                ident[(size_t)n * 64 + lane] = ai[r] + rbv;
                if ((lane & 7) == 0) {
                    a_src[n * 8 + (lane >> 3)] = ps;
                    a_dst[n * 8 + (lane >> 3)] = pd;
                }
            }
        }
    }
}

// ---------------- K2: edge pass. Wave owns 64 consecutive edges. ------------
// Cooperative coalesced loads of src/dst/ea (one per lane), then 8 groups of 8
// edges: readlane broadcasts + 8 independent h-gathers in flight -> 8x MLP.
// o_raw[d] += num*h[s] (pk-bf16x2 atomics, even lanes); denom[d] += num (f32).
__global__ __launch_bounds__(256) void k2_edge(
    const int* __restrict__ ei, const float* __restrict__ ea,
    const ushort_t* __restrict__ h, const float* __restrict__ a_src,
    const float* __restrict__ a_dst, const float* __restrict__ W_edge,
    const float* __restrict__ att_edge,
    float* __restrict__ denom, ushort_t* __restrict__ out_raw)
{
    const int lane = threadIdx.x & 63;
    const int hd = lane >> 3;
    // AE fold: ae_d = sum_c W_edge[d][hd*8+c] * att_edge[hd][c]  (tiny, cached)
    float ae0 = 0.f, ae1 = 0.f, ae2 = 0.f, ae3 = 0.f;
    #pragma unroll
    for (int c2 = 0; c2 < 8; ++c2) {
        const float a = att_edge[hd * 8 + c2];
        ae0 = fmaf(W_edge[0 * 64 + hd * 8 + c2], a, ae0);
        ae1 = fmaf(W_edge[1 * 64 + hd * 8 + c2], a, ae1);
        ae2 = fmaf(W_edge[2 * 64 + hd * 8 + c2], a, ae2);
        ae3 = fmaf(W_edge[3 * 64 + hd * 8 + c2], a, ae3);
    }

    const int gwave = blockIdx.x * 4 + (threadIdx.x >> 6);
    const int nwave = gridDim.x * 4;
    for (int base = gwave * 64; base < N_EDGES; base += nwave * 64) {
        const int vsrc = ei[base + lane];                 // coalesced
        const int vdst = ei[N_EDGES + base + lane];       // coalesced
        const float4 vea = *reinterpret_cast<const float4*>(ea + (size_t)(base + lane) * 4);
        for (int g = 0; g < 64; g += 8) {
            int s[8], d[8];
            float e0[8], e1[8], e2[8], e3[8];
            #pragma unroll
            for (int j = 0; j < 8; ++j) {
                s[j] = __builtin_amdgcn_readlane(vsrc, g + j);
                d[j] = __builtin_amdgcn_readlane(vdst, g + j);
                e0[j] = rlane(vea.x, g + j);
                e1[j] = rlane(vea.y, g + j);
                e2[j] = rlane(vea.z, g + j);
                e3[j] = rlane(vea.w, g + j);
            }
            float hv[8], as8[8], ad8[8];
            #pragma unroll
            for (int j = 0; j < 8; ++j) {     // 24 independent loads in flight
                hv[j]  = bf2f(h[(size_t)s[j] * 64 + lane]);
                as8[j] = a_src[s[j] * 8 + hd];
                ad8[j] = a_dst[d[j] * 8 + hd];
            }
            #pragma unroll
            for (int j = 0; j < 8; ++j) {
                float logit = as8[j] + ad8[j]
                            + e0[j] * ae0 + e1[j] * ae1 + e2[j] * ae2 + e3[j] * ae3;
                logit = logit > 0.f ? logit : 0.2f * logit;   // leaky_relu 0.2
                const float num = __expf(logit);              // no max-shift needed
                const float v = num * hv[j];
                const float vn = __shfl_xor(v, 1);
                if ((lane & 1) == 0) {
                    const unsigned packed = (unsigned)f2bf(v) | ((unsigned)f2bf(vn) << 16);
                    atomic_pk_add_bf16(out_raw + (size_t)d[j] * 64 + lane, packed);
                }
                if ((lane & 7) == 0) atomicAdd(&denom[d[j] * 8 + hd], num);
            }
        }
    }
    // Drain asm-issued atomics before wave exit: the compiler's end-of-kernel
    // waitcnt doesn't know about them; without this, k3 can observe o_raw
    // before all pk-adds have landed (lost-update race under replay pressure).
    asm volatile("s_waitcnt vmcnt(0)" ::: "memory");
}

// ---------------- K3: BN partial stats from v = o_raw/denom + bias (no store) -
__global__ __launch_bounds__(256) void k3_stats(
    const ushort_t* __restrict__ out_raw, const float* __restrict__ denom,
    const float* __restrict__ bias,
    float* __restrict__ bn_acc /* [128]: sum(64), sumsq(64) */)
{
    const int tid = threadIdx.x;
    const int c = tid & 63;
    const float b = bias[c];
    float s1 = 0.f, s2 = 0.f;
    const int stride = gridDim.x * 4;
    for (int n = blockIdx.x * 4 + (tid >> 6); n < N_NODES; n += stride) {
        const float v = bf2f(out_raw[(size_t)n * 64 + c])
                        / (denom[n * 8 + (c >> 3)] + 1e-16f) + b;
        s1 += v; s2 += v * v;
    }
    __shared__ float r1[256], r2[256];
    r1[tid] = s1; r2[tid] = s2;
    __syncthreads();
    if (tid < 64) {
        s1 = r1[tid] + r1[tid + 64] + r1[tid + 128] + r1[tid + 192];
        s2 = r2[tid] + r2[tid + 64] + r2[tid + 128] + r2[tid + 192];
        atomicAdd(&bn_acc[c], s1);
        atomicAdd(&bn_acc[64 + c], s2);
    }
}

// ---------------- K4: stats -> scale/shift, recompute v, BN+ELU+residual -----
__global__ __launch_bounds__(256) void k4_final(
    float* __restrict__ out, const ushort_t* __restrict__ out_raw,
    const float* __restrict__ denom, const float* __restrict__ bias,
    const float* __restrict__ bn_acc, const float* __restrict__ bn_w,
    const float* __restrict__ bn_b)
{
    const int tid = threadIdx.x;
    const int c = tid & 63;
    const float b = bias[c];
    const float inv_n = 1.0f / (float)N_NODES;
    const float mean = bn_acc[c] * inv_n;
    const float var = bn_acc[64 + c] * inv_n - mean * mean;   // biased var
    const float sc = bn_w[c] * rsqrtf(var + 1e-5f);
    const float sh = bn_b[c] - mean * sc;
    const int stride = gridDim.x * 4;
    for (int n = blockIdx.x * 4 + (tid >> 6); n < N_NODES; n += stride) {
        float v = bf2f(out_raw[(size_t)n * 64 + c])
                  / (denom[n * 8 + (c >> 3)] + 1e-16f) + b;
        v = v * sc + sh;
        v = v > 0.f ? v : __expf(v) - 1.f;            // ELU
        out[(size_t)n * 64 + c] = v + out[(size_t)n * 64 + c];  // + ident
    }
}

extern "C" void kernel_launch(void* const* d_in, const int* in_sizes, int n_in,
                              void* d_out, int out_size, void* d_ws, size_t ws_size,
                              hipStream_t stream) {
    const float* x        = (const float*)d_in[0];
    const int*   ei       = (const int*)  d_in[1];
    const float* ea       = (const float*)d_in[2];
    const float* W        = (const float*)d_in[3];
    const float* att_src  = (const float*)d_in[4];
    const float* att_dst  = (const float*)d_in[5];
    const float* W_edge   = (const float*)d_in[6];
    const float* att_edge = (const float*)d_in[7];
    const float* bias     = (const float*)d_in[8];
    const float* bn_w     = (const float*)d_in[9];
    const float* bn_b     = (const float*)d_in[10];
    const float* res_W    = (const float*)d_in[11];
    const float* res_b    = (const float*)d_in[12];

    char* ws = (char*)d_ws;
    size_t off = 0;
    ushort_t* h   = (ushort_t*)(ws + off); off += (size_t)N_NODES * 64 * 2;
    float* a_src  = (float*)(ws + off); off += (size_t)N_NODES * 8 * 4;
    float* a_dst  = (float*)(ws + off); off += (size_t)N_NODES * 8 * 4;
    char*  zstart = ws + off;
    float* denom  = (float*)(ws + off); off += (size_t)N_NODES * 8 * 4;
    ushort_t* o_raw = (ushort_t*)(ws + off); off += (size_t)N_NODES * 64 * 2;
    float* bn_acc = (float*)(ws + off); off += 128 * 4;
    size_t zbytes = (size_t)((ws + off) - zstart);

    float* ident = (float*)d_out;  // K1 writes residual GEMV here; K4 fuses in place

    (void)hipMemsetAsync(zstart, 0, zbytes, stream);
    k1_node<<<(N_NODES + 127) / 128, 256, 0, stream>>>(
        x, W, res_W, att_src, att_dst, res_b, h, ident, a_src, a_dst);
    k2_edge<<<6250, 256, 0, stream>>>(ei, ea, h, a_src, a_dst, W_edge, att_edge,
                                      denom, o_raw);
    k3_stats<<<2048, 256, 0, stream>>>(o_raw, denom, bias, bn_acc);
    k4_final<<<2048, 256, 0, stream>>>((float*)d_out, o_raw, denom, bias,
                                       bn_acc, bn_w, bn_b);
}

// Round 11
// 484.327 us; speedup vs baseline: 1.5097x; 1.1425x over previous
//
#include <hip/hip_runtime.h>
#include <hip/hip_bf16.h>

#define N_NODES 100000
#define N_EDGES 1600000
// IN_C=128, HEADS=8, OUT_C=8, ACTUAL_OUT=64, EDGE_DIM=4
// 100000 = 3125 row-tiles x 32 rows exactly (no edge guards in k1)

typedef unsigned short ushort_t;
typedef __attribute__((ext_vector_type(4))) float f32x4;
typedef __attribute__((ext_vector_type(8))) short bf16x8v;

__device__ __forceinline__ float rlane(float v, int l) {
    return __int_as_float(__builtin_amdgcn_readlane(__float_as_int(v), l));
}
// f32 -> bf16 bits (round-nearest-even), and back
__device__ __forceinline__ ushort_t f2bf(float f) {
    unsigned u = __float_as_uint(f);
    u += 0x7FFFu + ((u >> 16) & 1u);
    return (ushort_t)(u >> 16);
}
__device__ __forceinline__ float bf2f(ushort_t b) {
    return __uint_as_float((unsigned)b << 16);
}
// packed bf16x2 atomic add, device scope (sc1). gfx950 HW instruction.
// NOTE: asm vmem op is invisible to the compiler's vmcnt bookkeeping -> caller
// MUST drain with s_waitcnt vmcnt(0) before wave exit (see end of k2_edge).
__device__ __forceinline__ void atomic_pk_add_bf16(ushort_t* addr, unsigned packed) {
    asm volatile("global_atomic_pk_add_bf16 %0, %1, off sc1"
                 :: "v"(addr), "v"(packed) : "memory");
}

// ---------------- K1 (MFMA): [h | ident] = bf16(x) @ bf16([W | res_W]) -------
// One wave per 32x128 output tile, grid-stride. B held in registers (32 frags,
// loaded once per wave from L2-hot W/res_W). A read coalesced from x, cvt to
// bf16 in-reg. Epilogue fuses h-store, ident+res_b store, a_src/a_dst reduce.
// Layouts (m89-verified C/D; ladder-verified consecutive-k A/B packing):
//   a[i] = A[row=lane&15][k=ks*32+(lane>>4)*8+i]
//   b[i] = B[k=ks*32+(lane>>4)*8+i][col=lane&15  (+16*fc)]
//   acc[r]: row=(lane>>4)*4+r, col=lane&15
__global__ __launch_bounds__(256) void k1_mfma(
    const float* __restrict__ x, const float* __restrict__ W,
    const float* __restrict__ resW, const float* __restrict__ att_src,
    const float* __restrict__ att_dst, const float* __restrict__ res_b,
    ushort_t* __restrict__ h, float* __restrict__ ident,
    float* __restrict__ a_src, float* __restrict__ a_dst)
{
    const int lane = threadIdx.x & 63;
    const int col = lane & 15;     // col within 16-wide frag
    const int kg  = lane >> 4;     // k-group (input) / row-group (output)

    // ---- B fragments: bfrag[ks][fc], fc<4 -> W (h cols), fc>=4 -> resW ----
    bf16x8v bfrag[4][8];
    #pragma unroll
    for (int ks = 0; ks < 4; ++ks) {
        #pragma unroll
        for (int fc = 0; fc < 8; ++fc) {
            const int j = (fc & 3) * 16 + col;            // col within 64
            const float* src = (fc < 4) ? (W + j) : (resW + j);
            bf16x8v b;
            #pragma unroll
            for (int i = 0; i < 8; ++i) {
                const int k = ks * 32 + kg * 8 + i;
                b[i] = (short)f2bf(src[k * 64]);
            }
            bfrag[ks][fc] = b;
        }
    }
    // per-lane epilogue constants
    float atts[4], attd[4], rb[4];
    #pragma unroll
    for (int fc = 0; fc < 4; ++fc) {
        atts[fc] = att_src[fc * 16 + col];
        attd[fc] = att_dst[fc * 16 + col];
        rb[fc]   = res_b[fc * 16 + col];
    }

    const int wid = blockIdx.x * 4 + (threadIdx.x >> 6);
    const int nw = gridDim.x * 4;
    for (int tile = wid; tile < 3125; tile += nw) {
        const int row0 = tile * 32;
        f32x4 acc[2][8];
        #pragma unroll
        for (int rt = 0; rt < 2; ++rt)
            #pragma unroll
            for (int fc = 0; fc < 8; ++fc)
                acc[rt][fc] = (f32x4){0.f, 0.f, 0.f, 0.f};

        #pragma unroll
        for (int ks = 0; ks < 4; ++ks) {
            bf16x8v afrag[2];
            #pragma unroll
            for (int rt = 0; rt < 2; ++rt) {
                const float* xr = x + (size_t)(row0 + rt * 16 + col) * 128 + ks * 32 + kg * 8;
                const float4 lo = *reinterpret_cast<const float4*>(xr);
                const float4 hi = *reinterpret_cast<const float4*>(xr + 4);
                bf16x8v a;
                a[0] = (short)f2bf(lo.x); a[1] = (short)f2bf(lo.y);
                a[2] = (short)f2bf(lo.z); a[3] = (short)f2bf(lo.w);
                a[4] = (short)f2bf(hi.x); a[5] = (short)f2bf(hi.y);
                a[6] = (short)f2bf(hi.z); a[7] = (short)f2bf(hi.w);
                afrag[rt] = a;
            }
            #pragma unroll
            for (int fc = 0; fc < 8; ++fc) {
                acc[0][fc] = __builtin_amdgcn_mfma_f32_16x16x32_bf16(
                    afrag[0], bfrag[ks][fc], acc[0][fc], 0, 0, 0);
                acc[1][fc] = __builtin_amdgcn_mfma_f32_16x16x32_bf16(
                    afrag[1], bfrag[ks][fc], acc[1][fc], 0, 0, 0);
            }
        }

        // ---- epilogue ----
        #pragma unroll
        for (int rt = 0; rt < 2; ++rt) {
            #pragma unroll
            for (int fc = 0; fc < 8; ++fc) {
                #pragma unroll
                for (int r = 0; r < 4; ++r) {
                    const int row = row0 + rt * 16 + kg * 4 + r;
                    const float val = acc[rt][fc][r];
                    if (fc < 4) {
                        h[(size_t)row * 64 + fc * 16 + col] = f2bf(val);
                        float ps = val * atts[fc];
                        float pd = val * attd[fc];
                        ps += __shfl_xor(ps, 1); ps += __shfl_xor(ps, 2); ps += __shfl_xor(ps, 4);
                        pd += __shfl_xor(pd, 1); pd += __shfl_xor(pd, 2); pd += __shfl_xor(pd, 4);
                        if ((lane & 7) == 0) {
                            const int hd = fc * 2 + (col >> 3);
                            a_src[row * 8 + hd] = ps;
                            a_dst[row * 8 + hd] = pd;
                        }
                    } else {
                        ident[(size_t)row * 64 + (fc - 4) * 16 + col] = val + rb[fc - 4];
                    }
                }
            }
        }
    }
}

// ---------------- K2: edge pass. Wave owns 64 consecutive edges. ------------
// Cooperative coalesced loads of src/dst/ea (one per lane), then 8 groups of 8
// edges: readlane broadcasts + 8 independent h-gathers in flight -> 8x MLP.
// o_raw[d] += num*h[s] (pk-bf16x2 atomics, even lanes); denom[d] += num (f32).
__global__ __launch_bounds__(256) void k2_edge(
    const int* __restrict__ ei, const float* __restrict__ ea,
    const ushort_t* __restrict__ h, const float* __restrict__ a_src,
    const float* __restrict__ a_dst, const float* __restrict__ W_edge,
    const float* __restrict__ att_edge,
    float* __restrict__ denom, ushort_t* __restrict__ out_raw)
{
    const int lane = threadIdx.x & 63;
    const int hd = lane >> 3;
    // AE fold: ae_d = sum_c W_edge[d][hd*8+c] * att_edge[hd][c]  (tiny, cached)
    float ae0 = 0.f, ae1 = 0.f, ae2 = 0.f, ae3 = 0.f;
    #pragma unroll
    for (int c2 = 0; c2 < 8; ++c2) {
        const float a = att_edge[hd * 8 + c2];
        ae0 = fmaf(W_edge[0 * 64 + hd * 8 + c2], a, ae0);
        ae1 = fmaf(W_edge[1 * 64 + hd * 8 + c2], a, ae1);
        ae2 = fmaf(W_edge[2 * 64 + hd * 8 + c2], a, ae2);
        ae3 = fmaf(W_edge[3 * 64 + hd * 8 + c2], a, ae3);
    }

    const int gwave = blockIdx.x * 4 + (threadIdx.x >> 6);
    const int nwave = gridDim.x * 4;
    for (int base = gwave * 64; base < N_EDGES; base += nwave * 64) {
        const int vsrc = ei[base + lane];                 // coalesced
        const int vdst = ei[N_EDGES + base + lane];       // coalesced
        const float4 vea = *reinterpret_cast<const float4*>(ea + (size_t)(base + lane) * 4);
        for (int g = 0; g < 64; g += 8) {
            int s[8], d[8];
            float e0[8], e1[8], e2[8], e3[8];
            #pragma unroll
            for (int j = 0; j < 8; ++j) {
                s[j] = __builtin_amdgcn_readlane(vsrc, g + j);
                d[j] = __builtin_amdgcn_readlane(vdst, g + j);
                e0[j] = rlane(vea.x, g + j);
                e1[j] = rlane(vea.y, g + j);
                e2[j] = rlane(vea.z, g + j);
                e3[j] = rlane(vea.w, g + j);
            }
            float hv[8], as8[8], ad8[8];
            #pragma unroll
            for (int j = 0; j < 8; ++j) {     // 24 independent loads in flight
                hv[j]  = bf2f(h[(size_t)s[j] * 64 + lane]);
                as8[j] = a_src[s[j] * 8 + hd];
                ad8[j] = a_dst[d[j] * 8 + hd];
            }
            #pragma unroll
            for (int j = 0; j < 8; ++j) {
                float logit = as8[j] + ad8[j]
                            + e0[j] * ae0 + e1[j] * ae1 + e2[j] * ae2 + e3[j] * ae3;
                logit = logit > 0.f ? logit : 0.2f * logit;   // leaky_relu 0.2
                const float num = __expf(logit);              // no max-shift needed
                const float v = num * hv[j];
                const float vn = __shfl_xor(v, 1);
                if ((lane & 1) == 0) {
                    const unsigned packed = (unsigned)f2bf(v) | ((unsigned)f2bf(vn) << 16);
                    atomic_pk_add_bf16(out_raw + (size_t)d[j] * 64 + lane, packed);
                }
                if ((lane & 7) == 0) atomicAdd(&denom[d[j] * 8 + hd], num);
            }
        }
    }
    // Drain asm-issued atomics before wave exit: the compiler's end-of-kernel
    // waitcnt doesn't know about them; without this, k3 can observe o_raw
    // before all pk-adds have landed (lost-update race under replay pressure).
    asm volatile("s_waitcnt vmcnt(0)" ::: "memory");
}

// ---------------- K3: BN partial stats from v = o_raw/denom + bias (no store) -
__global__ __launch_bounds__(256) void k3_stats(
    const ushort_t* __restrict__ out_raw, const float* __restrict__ denom,
    const float* __restrict__ bias,
    float* __restrict__ bn_acc /* [128]: sum(64), sumsq(64) */)
{
    const int tid = threadIdx.x;
    const int c = tid & 63;
    const float b = bias[c];
    float s1 = 0.f, s2 = 0.f;
    const int stride = gridDim.x * 4;
    for (int n = blockIdx.x * 4 + (tid >> 6); n < N_NODES; n += stride) {
        const float v = bf2f(out_raw[(size_t)n * 64 + c])
                        / (denom[n * 8 + (c >> 3)] + 1e-16f) + b;
        s1 += v; s2 += v * v;
    }
    __shared__ float r1[256], r2[256];
    r1[tid] = s1; r2[tid] = s2;
    __syncthreads();
    if (tid < 64) {
        s1 = r1[tid] + r1[tid + 64] + r1[tid + 128] + r1[tid + 192];
        s2 = r2[tid] + r2[tid + 64] + r2[tid + 128] + r2[tid + 192];
        atomicAdd(&bn_acc[c], s1);
        atomicAdd(&bn_acc[64 + c], s2);
    }
}

// ---------------- K4: stats -> scale/shift, recompute v, BN+ELU+residual -----
__global__ __launch_bounds__(256) void k4_final(
    float* __restrict__ out, const ushort_t* __restrict__ out_raw,
    const float* __restrict__ denom, const float* __restrict__ bias,
    const float* __restrict__ bn_acc, const float* __restrict__ bn_w,
    const float* __restrict__ bn_b)
{
    const int tid = threadIdx.x;
    const int c = tid & 63;
    const float b = bias[c];
    const float inv_n = 1.0f / (float)N_NODES;
    const float mean = bn_acc[c] * inv_n;
    const float var = bn_acc[64 + c] * inv_n - mean * mean;   // biased var
    const float sc = bn_w[c] * rsqrtf(var + 1e-5f);
    const float sh = bn_b[c] - mean * sc;
    const int stride = gridDim.x * 4;
    for (int n = blockIdx.x * 4 + (tid >> 6); n < N_NODES; n += stride) {
        float v = bf2f(out_raw[(size_t)n * 64 + c])
                  / (denom[n * 8 + (c >> 3)] + 1e-16f) + b;
        v = v * sc + sh;
        v = v > 0.f ? v : __expf(v) - 1.f;            // ELU
        out[(size_t)n * 64 + c] = v + out[(size_t)n * 64 + c];  // + ident
    }
}

extern "C" void kernel_launch(void* const* d_in, const int* in_sizes, int n_in,
                              void* d_out, int out_size, void* d_ws, size_t ws_size,
                              hipStream_t stream) {
    const float* x        = (const float*)d_in[0];
    const int*   ei       = (const int*)  d_in[1];
    const float* ea       = (const float*)d_in[2];
    const float* W        = (const float*)d_in[3];
    const float* att_src  = (const float*)d_in[4];
    const float* att_dst  = (const float*)d_in[5];
    const float* W_edge   = (const float*)d_in[6];
    const float* att_edge = (const float*)d_in[7];
    const float* bias     = (const float*)d_in[8];
    const float* bn_w     = (const float*)d_in[9];
    const float* bn_b     = (const float*)d_in[10];
    const float* res_W    = (const float*)d_in[11];
    const float* res_b    = (const float*)d_in[12];

    char* ws = (char*)d_ws;
    size_t off = 0;
    ushort_t* h   = (ushort_t*)(ws + off); off += (size_t)N_NODES * 64 * 2;
    float* a_src  = (float*)(ws + off); off += (size_t)N_NODES * 8 * 4;
    float* a_dst  = (float*)(ws + off); off += (size_t)N_NODES * 8 * 4;
    char*  zstart = ws + off;
    float* denom  = (float*)(ws + off); off += (size_t)N_NODES * 8 * 4;
    ushort_t* o_raw = (ushort_t*)(ws + off); off += (size_t)N_NODES * 64 * 2;
    float* bn_acc = (float*)(ws + off); off += 128 * 4;
    size_t zbytes = (size_t)((ws + off) - zstart);

    float* ident = (float*)d_out;  // K1 writes residual GEMV here; K4 fuses in place

    (void)hipMemsetAsync(zstart, 0, zbytes, stream);
    k1_mfma<<<512, 256, 0, stream>>>(
        x, W, res_W, att_src, att_dst, res_b, h, ident, a_src, a_dst);
    k2_edge<<<6250, 256, 0, stream>>>(ei, ea, h, a_src, a_dst, W_edge, att_edge,
                                      denom, o_raw);
    k3_stats<<<2048, 256, 0, stream>>>(o_raw, denom, bias, bn_acc);
    k4_final<<<2048, 256, 0, stream>>>((float*)d_out, o_raw, denom, bias,
                                       bn_acc, bn_w, bn_b);
}